// Round 1
// baseline (52.150 us; speedup 1.0000x reference)
//
#include <hip/hip_runtime.h>
#include <math.h>

#define N_CG  50000
#define APC   13
#define N_AT  (N_CG * APC)
#define FEAT  128
#define DEG   16
#define VOCAB 100

// P[z][f] = (z != 0 ? emb[z] : 0) @ W_msg   -> 100 x 128
__global__ void p_kernel(const float* __restrict__ emb,
                         const float* __restrict__ Wmsg,
                         float* __restrict__ P) {
    int z = blockIdx.x;    // 0..99
    int f = threadIdx.x;   // 0..127
    float acc = 0.f;
    #pragma unroll 8
    for (int k = 0; k < FEAT; ++k)
        acc += emb[z * FEAT + k] * Wmsg[k * FEAT + f];
    P[z * FEAT + f] = (z != 0) ? acc : 0.f;
}

// T[zi*VOCAB+zj][c] = silu(P[zi] + P[zj]) @ W_vec   -> 10000 x 13
__global__ void table_kernel(const float* __restrict__ P,
                             const float* __restrict__ Wvec,
                             float* __restrict__ T) {
    int row = blockIdx.x;              // zi*VOCAB + zj
    int zi = row / VOCAB, zj = row % VOCAB;
    int t = threadIdx.x;               // 0..127
    __shared__ float hs[FEAT];
    __shared__ float part[APC * 8];
    float h = P[zi * FEAT + t] + P[zj * FEAT + t];
    hs[t] = h / (1.f + expf(-h));      // silu
    __syncthreads();
    if (t < APC * 8) {
        int c = t >> 3, g = t & 7;     // c: 0..12, g: 0..7 (16-wide k slabs)
        int k0 = g * 16;
        float p = 0.f;
        #pragma unroll
        for (int k = 0; k < 16; ++k)
            p += hs[k0 + k] * Wvec[(k0 + k) * APC + c];
        part[c * 8 + g] = p;
    }
    __syncthreads();
    if (t < APC) {
        float s = 0.f;
        #pragma unroll
        for (int g = 0; g < 8; ++g) s += part[t * 8 + g];
        T[row * APC + t] = s;
    }
}

// One thread per output atom: accumulate its channel of the segment-sum
// over the cg's 16 contiguous edges, then add cg_xyz (ca channel zeroed).
__global__ void recon_kernel(const float* __restrict__ xyz,
                             const int*   __restrict__ nbr,
                             const int*   __restrict__ cg_z,
                             const int*   __restrict__ mapping,
                             const int*   __restrict__ ca_idx,
                             const float* __restrict__ T,
                             float* __restrict__ out) {
    int a = blockIdx.x * blockDim.x + threadIdx.x;
    if (a >= N_AT) return;
    int cg = mapping[a];
    int c  = a - (ca_idx[cg] - 1);     // ca_idx = first+1 -> channel in [0,13)
    float xi0 = xyz[cg * 3 + 0];
    float xi1 = xyz[cg * 3 + 1];
    float xi2 = xyz[cg * 3 + 2];
    int zi = cg_z[cg];
    const float* Tz = T + (size_t)zi * VOCAB * APC + c;
    float a0 = 0.f, a1 = 0.f, a2 = 0.f;
    #pragma unroll 4
    for (int k = 0; k < DEG; ++k) {
        int e = cg * DEG + k;          // src = repeat(arange(N_CG), DEG)
        int j = nbr[2 * e + 1];
        float dx = xyz[j * 3 + 0] - xi0;
        float dy = xyz[j * 3 + 1] - xi1;
        float dz = xyz[j * 3 + 2] - xi2;
        float nrm = sqrtf(dx * dx + dy * dy + dz * dz);
        float inv = 1.f / (nrm + 1e-8f);
        int zj = cg_z[j];
        float w = Tz[(size_t)zj * APC] * inv;
        a0 += w * dx;
        a1 += w * dy;
        a2 += w * dz;
    }
    if (c == 1) { a0 = 0.f; a1 = 0.f; a2 = 0.f; }  // ca atom: rel = 0
    out[a * 3 + 0] = a0 + xi0;
    out[a * 3 + 1] = a1 + xi1;
    out[a * 3 + 2] = a2 + xi2;
}

extern "C" void kernel_launch(void* const* d_in, const int* in_sizes, int n_in,
                              void* d_out, int out_size, void* d_ws, size_t ws_size,
                              hipStream_t stream) {
    const float* cg_xyz  = (const float*)d_in[0];
    const float* emb     = (const float*)d_in[1];
    const float* W_msg   = (const float*)d_in[2];
    const float* W_vec   = (const float*)d_in[3];
    const int*   cg_z    = (const int*)d_in[4];
    const int*   nbr     = (const int*)d_in[5];
    const int*   mapping = (const int*)d_in[6];
    const int*   ca_idx  = (const int*)d_in[7];
    float* out = (float*)d_out;

    float* P = (float*)d_ws;               // 100*128*4   = 51.2 KB
    float* T = P + VOCAB * FEAT;           // 10000*13*4  = 520 KB

    p_kernel<<<VOCAB, FEAT, 0, stream>>>(emb, W_msg, P);
    table_kernel<<<VOCAB * VOCAB, FEAT, 0, stream>>>(P, W_vec, T);
    recon_kernel<<<(N_AT + 255) / 256, 256, 0, stream>>>(
        cg_xyz, nbr, cg_z, mapping, ca_idx, T, out);
}

// Round 2
// 34.103 us; speedup vs baseline: 1.5292x; 1.5292x over previous
//
#include <hip/hip_runtime.h>
#include <math.h>

#define N_CG   50000
#define APC    13
#define N_AT   (N_CG * APC)
#define FEAT   128
#define DEG    16
#define VOCAB  100
#define TPAD   16          // padded row stride of T (floats)
#define CG_PER_BLK 16      // recon: cgs per block
#define ROWS_PER_BLK 16    // table: rows per block

// P[z][f] = (z != 0 ? emb[z] : 0) @ W_msg   -> 100 x 128
__global__ void p_kernel(const float* __restrict__ emb,
                         const float* __restrict__ Wmsg,
                         float* __restrict__ P) {
    int z = blockIdx.x;    // 0..99
    int f = threadIdx.x;   // 0..127
    float acc = 0.f;
    #pragma unroll 8
    for (int k = 0; k < FEAT; ++k)
        acc += emb[z * FEAT + k] * Wmsg[k * FEAT + f];
    P[z * FEAT + f] = (z != 0) ? acc : 0.f;
}

// T[row][c] = silu(P[zi] + P[zj]) @ W_vec, row = zi*VOCAB+zj, padded stride 16
__global__ void table_kernel(const float* __restrict__ P,
                             const float* __restrict__ Wvec,
                             float* __restrict__ T) {
    __shared__ float hs[ROWS_PER_BLK][FEAT + 1];   // +1 pad: phase-B reads stride 516B
    int t = threadIdx.x;                           // 0..255
    int row0 = blockIdx.x * ROWS_PER_BLK;

    // Phase A: 16 rows x 128 silu values, 8 per thread
    #pragma unroll
    for (int i = 0; i < (ROWS_PER_BLK * FEAT) / 256; ++i) {
        int v = t + i * 256;
        int r = v >> 7, f = v & 127;
        int row = row0 + r;
        int zi = row / VOCAB, zj = row % VOCAB;
        float h = P[zi * FEAT + f] + P[zj * FEAT + f];
        hs[r][f] = h / (1.f + expf(-h));
    }
    __syncthreads();

    // Phase B: 16 rows x 13 channels = 208 threads
    if (t < ROWS_PER_BLK * APC) {
        int r = t / APC, c = t % APC;
        float s = 0.f;
        #pragma unroll 8
        for (int f = 0; f < FEAT; ++f)
            s += hs[r][f] * Wvec[f * APC + c];
        T[(size_t)(row0 + r) * TPAD + c] = s;
    }
}

// Fused segment-sum + reconstruction.
// Block = 16 cgs. Phase 1: 256 threads compute the 256 edges' unit vectors
// (premultiplied by 1/(|r|+eps)) and T-row indices once, into LDS.
// Phase 2: 208 threads (cg, channel) accumulate 16 edges and write out.
__global__ void recon_kernel(const float* __restrict__ xyz,
                             const int*   __restrict__ nbr,
                             const int*   __restrict__ cg_z,
                             const int*   __restrict__ ca_idx,
                             const float* __restrict__ T,
                             float* __restrict__ out) {
    __shared__ float4 eu[CG_PER_BLK][DEG + 1];   // pad -> 272B row stride
    __shared__ int  erow[CG_PER_BLK][DEG + 1];

    int t = threadIdx.x;
    int cg0 = blockIdx.x * CG_PER_BLK;

    // Phase 1: one edge per thread
    {
        int g = t >> 4;            // cg within block
        int k = t & 15;            // edge within cg
        int cg = cg0 + g;
        int e = cg * DEG + k;      // src = repeat(arange(N_CG), DEG)
        int j = nbr[2 * e + 1];
        float xi0 = xyz[cg * 3 + 0];
        float xi1 = xyz[cg * 3 + 1];
        float xi2 = xyz[cg * 3 + 2];
        float dx = xyz[j * 3 + 0] - xi0;
        float dy = xyz[j * 3 + 1] - xi1;
        float dz = xyz[j * 3 + 2] - xi2;
        float inv = 1.f / (sqrtf(dx * dx + dy * dy + dz * dz) + 1e-8f);
        int zi = cg_z[cg];
        int zj = cg_z[j];
        eu[g][k] = make_float4(dx * inv, dy * inv, dz * inv, 0.f);
        erow[g][k] = zi * VOCAB + zj;
    }
    __syncthreads();

    // Phase 2: one (cg, channel) per thread
    if (t < CG_PER_BLK * APC) {
        int g = t / APC, c = t % APC;
        int cg = cg0 + g;
        float a0 = 0.f, a1 = 0.f, a2 = 0.f;
        #pragma unroll
        for (int k = 0; k < DEG; ++k) {
            float4 u = eu[g][k];
            int row = erow[g][k];
            float w = T[(size_t)row * TPAD + c];
            a0 += w * u.x;
            a1 += w * u.y;
            a2 += w * u.z;
        }
        if (c == 1) { a0 = 0.f; a1 = 0.f; a2 = 0.f; }   // ca atom: rel = 0
        int a = (ca_idx[cg] - 1) + c;                   // first + channel
        float xi0 = xyz[cg * 3 + 0];
        float xi1 = xyz[cg * 3 + 1];
        float xi2 = xyz[cg * 3 + 2];
        out[a * 3 + 0] = a0 + xi0;
        out[a * 3 + 1] = a1 + xi1;
        out[a * 3 + 2] = a2 + xi2;
    }
}

extern "C" void kernel_launch(void* const* d_in, const int* in_sizes, int n_in,
                              void* d_out, int out_size, void* d_ws, size_t ws_size,
                              hipStream_t stream) {
    const float* cg_xyz  = (const float*)d_in[0];
    const float* emb     = (const float*)d_in[1];
    const float* W_msg   = (const float*)d_in[2];
    const float* W_vec   = (const float*)d_in[3];
    const int*   cg_z    = (const int*)d_in[4];
    const int*   nbr     = (const int*)d_in[5];
    const int*   ca_idx  = (const int*)d_in[7];
    float* out = (float*)d_out;

    float* P = (float*)d_ws;               // 100*128*4          = 51.2 KB
    float* T = P + VOCAB * FEAT;           // 10000*16*4 (padded)= 640 KB

    p_kernel<<<VOCAB, FEAT, 0, stream>>>(emb, W_msg, P);
    table_kernel<<<(VOCAB * VOCAB) / ROWS_PER_BLK, 256, 0, stream>>>(P, W_vec, T);
    recon_kernel<<<N_CG / CG_PER_BLK, 256, 0, stream>>>(
        cg_xyz, nbr, cg_z, ca_idx, T, out);
}